// Round 4
// baseline (435.089 us; speedup 1.0000x reference)
//
#include <hip/hip_runtime.h>

#define HH 2048
#define WW 2048
constexpr float DT = 0.01f;
constexpr float VISC = 0.001f;

// ---------------------------------------------------------------- bilerp ----
// Exact replica of the reference _bilerp, including the degenerate case where
// clipping makes x0==x1 (or y0==y1): weights then sum to 0 and result is 0.
__device__ __forceinline__ float bilerp(const float* __restrict__ f, int h, int w,
                                        float y, float x) {
    int x0 = (int)floorf(x);
    int y0 = (int)floorf(y);
    int x1 = x0 + 1, y1 = y0 + 1;
    x0 = min(max(x0, 0), w - 1);
    x1 = min(max(x1, 0), w - 1);
    y0 = min(max(y0, 0), h - 1);
    y1 = min(max(y1, 0), h - 1);
    float x0f = (float)x0, x1f = (float)x1, y0f = (float)y0, y1f = (float)y1;
    float wa = (x1f - x) * (y1f - y);
    float wb = (x - x0f) * (y1f - y);
    float wc = (x1f - x) * (y - y0f);
    float wd = (x - x0f) * (y - y0f);
    return wa * f[y0 * w + x0] + wb * f[y0 * w + x1] +
           wc * f[y1 * w + x0] + wd * f[y1 * w + x1];
}

// --------------------------------------------------------------- diffuse ----
__global__ void k_diffuse_u(const float* __restrict__ u, float* __restrict__ out) {
    int j = blockIdx.x * blockDim.x + threadIdx.x;
    int i = blockIdx.y;
    const int h = HH + 1, w = WW;
    if (j >= w) return;
    int jm = max(j - 1, 0), jp = min(j + 1, w - 1);
    int im = max(i - 1, 0), ip = min(i + 1, h - 1);
    float c = u[(size_t)i * w + j];
    float lap = u[(size_t)im * w + j] + u[(size_t)ip * w + j] +
                u[(size_t)i * w + jm] + u[(size_t)i * w + jp] - 4.0f * c;
    out[(size_t)i * w + j] = c + (DT * VISC) * lap;
}

__device__ __forceinline__ float v_forced(const float* __restrict__ v,
                                          const float* __restrict__ den,
                                          int i, int j) {
    // v: (HH, WW+1); force DT*(den*0.1) applied to cols [0, WW)
    float val = v[(size_t)i * (WW + 1) + j];
    if (j < WW) val += DT * (den[(size_t)i * WW + j] * 0.1f);
    return val;
}

__global__ void k_diffuse_v(const float* __restrict__ v, const float* __restrict__ den,
                            float* __restrict__ out) {
    int j = blockIdx.x * blockDim.x + threadIdx.x;
    int i = blockIdx.y;
    const int h = HH, w = WW + 1;
    if (j >= w) return;
    int jm = max(j - 1, 0), jp = min(j + 1, w - 1);
    int im = max(i - 1, 0), ip = min(i + 1, h - 1);
    float c = v_forced(v, den, i, j);
    float lap = v_forced(v, den, im, j) + v_forced(v, den, ip, j) +
                v_forced(v, den, i, jm) + v_forced(v, den, i, jp) - 4.0f * c;
    out[(size_t)i * w + j] = c + (DT * VISC) * lap;
}

__global__ void k_diffuse_d(const float* __restrict__ d, float* __restrict__ out) {
    int j = blockIdx.x * blockDim.x + threadIdx.x;
    int i = blockIdx.y;
    const int h = HH, w = WW;
    if (j >= w) return;
    int jm = max(j - 1, 0), jp = min(j + 1, w - 1);
    int im = max(i - 1, 0), ip = min(i + 1, h - 1);
    float c = d[(size_t)i * w + j];
    float lap = d[(size_t)im * w + j] + d[(size_t)ip * w + j] +
                d[(size_t)i * w + jm] + d[(size_t)i * w + jp] - 4.0f * c;
    out[(size_t)i * w + j] = c + (DT * (VISC * 0.1f)) * lap;
}

// ------------------------------------------------------------ divergence ----
__global__ void k_div(const float* __restrict__ u, const float* __restrict__ v,
                      float* __restrict__ dv) {
    int j = blockIdx.x * blockDim.x + threadIdx.x;
    int i = blockIdx.y;
    if (j >= WW) return;
    float val = (u[(size_t)(i + 1) * WW + j] - u[(size_t)i * WW + j] +
                 v[(size_t)i * (WW + 1) + j + 1] - v[(size_t)i * (WW + 1) + j]) / DT;
    dv[(size_t)i * WW + j] = val;
}

// ---------------------------------------------------------------- jacobi ----
__global__ void k_jacobi_first(const float* __restrict__ dv, float* __restrict__ p) {
    int j = blockIdx.x * blockDim.x + threadIdx.x;
    int i = blockIdx.y;
    if (j >= WW) return;
    bool inner = (i > 0) && (i < HH - 1) && (j > 0) && (j < WW - 1);
    p[(size_t)i * WW + j] = inner ? (-0.25f * dv[(size_t)i * WW + j]) : 0.0f;
}

__global__ void k_jacobi(const float* __restrict__ pin, const float* __restrict__ dv,
                         float* __restrict__ pout) {
    int j = blockIdx.x * blockDim.x + threadIdx.x;
    int i = blockIdx.y;
    if (j >= WW) return;
    float val = 0.0f;
    if ((i > 0) && (i < HH - 1) && (j > 0) && (j < WW - 1)) {
        val = 0.25f * (pin[(size_t)(i - 1) * WW + j] + pin[(size_t)(i + 1) * WW + j] +
                       pin[(size_t)i * WW + j - 1] + pin[(size_t)i * WW + j + 1] -
                       dv[(size_t)i * WW + j]);
    }
    pout[(size_t)i * WW + j] = val;
}

// --------------------------------------------------------------- project ----
__global__ void k_project_u(float* __restrict__ u, const float* __restrict__ p) {
    int j = blockIdx.x * blockDim.x + threadIdx.x;
    int i = blockIdx.y + 1;  // rows 1..HH-1 of u (u has HH+1 rows)
    if (j >= WW) return;
    u[(size_t)i * WW + j] -= DT * (p[(size_t)i * WW + j] - p[(size_t)(i - 1) * WW + j]);
}

__global__ void k_project_v(float* __restrict__ v, const float* __restrict__ p) {
    int j = blockIdx.x * blockDim.x + threadIdx.x + 1;  // cols 1..WW-1 of v
    int i = blockIdx.y;
    if (j > WW - 1) return;
    v[(size_t)i * (WW + 1) + j] -= DT * (p[(size_t)i * WW + j] - p[(size_t)i * WW + j - 1]);
}

// ---------------------------------------------------------------- advect ----
__global__ void k_advect_u(const float* __restrict__ uf, const float* __restrict__ vf,
                           float* __restrict__ out) {
    int j = blockIdx.x * blockDim.x + threadIdx.x;
    int i = blockIdx.y;
    const int h = HH + 1, w = WW;
    if (j >= w) return;
    float X = (float)j, Y = (float)i;
    float x_u = fminf(fmaxf(X + 0.5f, 0.0f), (float)(WW - 1));
    float u_i = bilerp(uf, HH + 1, WW, Y, x_u);
    float y_v = fminf(fmaxf(Y + 0.5f, 0.0f), (float)(HH - 1));
    float v_i = bilerp(vf, HH, WW + 1, y_v, X);
    float px = fminf(fmaxf(X - DT * u_i, 0.0f), (float)(w - 1));
    float py = fminf(fmaxf(Y - DT * v_i, 0.0f), (float)(h - 1));
    out[(size_t)i * w + j] = bilerp(uf, h, w, py, px);
}

__global__ void k_advect_v(const float* __restrict__ vf, const float* __restrict__ un,
                           float* __restrict__ out) {
    int j = blockIdx.x * blockDim.x + threadIdx.x;
    int i = blockIdx.y;
    const int h = HH, w = WW + 1;
    if (j >= w) return;
    float X = (float)j, Y = (float)i;
    float x_u = fminf(fmaxf(X + 0.5f, 0.0f), (float)(WW - 1));
    float u_i = bilerp(un, HH + 1, WW, Y, x_u);
    float y_v = fminf(fmaxf(Y + 0.5f, 0.0f), (float)(HH - 1));
    float v_i = bilerp(vf, HH, WW + 1, y_v, X);
    float px = fminf(fmaxf(X - DT * u_i, 0.0f), (float)(w - 1));
    float py = fminf(fmaxf(Y - DT * v_i, 0.0f), (float)(h - 1));
    out[(size_t)i * w + j] = bilerp(vf, h, w, py, px);
}

__global__ void k_advect_d(const float* __restrict__ df, const float* __restrict__ un,
                           const float* __restrict__ vn, float* __restrict__ out) {
    int j = blockIdx.x * blockDim.x + threadIdx.x;
    int i = blockIdx.y;
    const int h = HH, w = WW;
    if (j >= w) return;
    float X = (float)j, Y = (float)i;
    float x_u = fminf(fmaxf(X + 0.5f, 0.0f), (float)(WW - 1));
    float u_i = bilerp(un, HH + 1, WW, Y, x_u);
    float y_v = fminf(fmaxf(Y + 0.5f, 0.0f), (float)(HH - 1));
    float v_i = bilerp(vn, HH, WW + 1, y_v, X);
    float px = fminf(fmaxf(X - DT * u_i, 0.0f), (float)(w - 1));
    float py = fminf(fmaxf(Y - DT * v_i, 0.0f), (float)(h - 1));
    out[(size_t)i * w + j] = 0.995f * bilerp(df, h, w, py, px);
}

// ---------------------------------------------------------------- launch ----
extern "C" void kernel_launch(void* const* d_in, const int* in_sizes, int n_in,
                              void* d_out, int out_size, void* d_ws, size_t ws_size,
                              hipStream_t stream) {
    const float* u_in   = (const float*)d_in[0];
    const float* v_in   = (const float*)d_in[1];
    const float* den_in = (const float*)d_in[2];
    // d_in[3] = p (all zeros) — not needed, first Jacobi iter is special-cased.
    float* out = (float*)d_out;

    const size_t SZ_UV = (size_t)(HH + 1) * WW;  // == HH*(WW+1)
    const size_t SZ_D  = (size_t)HH * WW;

    float* ws = (float*)d_ws;
    float* uA = ws;  ws += SZ_UV;
    float* uB = ws;  ws += SZ_UV;
    float* vA = ws;  ws += SZ_UV;
    float* vB = ws;  ws += SZ_UV;
    float* dA = ws;  ws += SZ_D;
    float* dv = ws;  ws += SZ_D;
    float* p0 = ws;  ws += SZ_D;
    float* p1 = ws;  ws += SZ_D;

    dim3 blk(256, 1, 1);
    dim3 gU((WW + 255) / 256, HH + 1);      // u-shaped: 2049 x 2048
    dim3 gV((WW + 1 + 255) / 256, HH);      // v-shaped: 2048 x 2049
    dim3 gD((WW + 255) / 256, HH);          // 2048 x 2048

    k_diffuse_u<<<gU, blk, 0, stream>>>(u_in, uA);
    k_diffuse_v<<<gV, blk, 0, stream>>>(v_in, den_in, vA);
    k_diffuse_d<<<gD, blk, 0, stream>>>(den_in, dA);

    k_div<<<gD, blk, 0, stream>>>(uA, vA, dv);

    k_jacobi_first<<<gD, blk, 0, stream>>>(dv, p1);
    float* pin = p1;
    float* pout = p0;
    for (int it = 1; it < 20; ++it) {
        k_jacobi<<<gD, blk, 0, stream>>>(pin, dv, pout);
        float* t = pin; pin = pout; pout = t;
    }
    // final pressure is in `pin`

    dim3 gPU((WW + 255) / 256, HH - 1);
    k_project_u<<<gPU, blk, 0, stream>>>(uA, pin);
    dim3 gPV((WW - 1 + 255) / 256, HH);
    k_project_v<<<gPV, blk, 0, stream>>>(vA, pin);

    k_advect_u<<<gU, blk, 0, stream>>>(uA, vA, uB);
    k_advect_v<<<gV, blk, 0, stream>>>(vA, uB, vB);
    k_advect_d<<<gD, blk, 0, stream>>>(dA, uB, vB, out);
}